// Round 14
// baseline (43.039 us; speedup 1.0000x reference)
//
#include <hip/hip_runtime.h>

// 2-bit child->parent distance per column c (50-bit word): d = (DPACK >> 2c) & 3.
// d==0 -> not a child. Parent of column c is column c-d (d<=3, same row).
#define DPACK 0x00012493939124E4ULL

struct P4 { float4 xa, xb, ta, tb; };

__device__ __forceinline__ float parsel(unsigned d, float w1, float w2, float w3) {
    return (d == 1u) ? w1 : (d == 2u) ? w2 : w3;   // caller masks d==0
}

__global__ __launch_bounds__(256)
void hbfl_kernel(const float* __restrict__ logits,
                 const float* __restrict__ targets,
                 float* __restrict__ partials,
                 unsigned n8, unsigned niter)
{
    __shared__ float wsum[4];

    const unsigned tid = threadIdx.x;
    const unsigned ln  = tid & 63u;
    const unsigned g0 = blockIdx.x * 256u + tid;      // pair-of-float4 index
    const unsigned stride = gridDim.x * 256u;         // 2050*256: 8*stride % 25 == 0

    // Loop-invariant per-thread column phase (8 consecutive elements).
    const unsigned c0 = (8u * g0) % 25u;
    unsigned d[8];
    #pragma unroll
    for (int j = 0; j < 8; ++j) {
        unsigned c = c0 + (unsigned)j;
        c = (c >= 25u) ? c - 25u : c;
        d[j] = (unsigned)(DPACK >> (2u * c)) & 3u;    // constant-index access only
    }

    const float4* l4p = reinterpret_cast<const float4*>(logits);
    const float4* t4p = reinterpret_cast<const float4*>(targets);

    // 4 loads per batch (tp load eliminated: was 20% of VMEM instructions /
    // requested bytes; its 3 used floats are the previous lane's tb.y/z/w).
    auto LOAD = [&](unsigned p, P4& v) {
        const unsigned q = 2u * p;
        v.xa = l4p[q];
        v.xb = l4p[q + 1u];
        v.ta = t4p[q];
        v.tb = t4p[q + 1u];
    };

    float acc = 0.0f;

    auto COMP = [&](const P4& v, unsigned p, bool valid) {
        // Prev thread's last 3 targets (flat elems 8p-3..8p-1) via cross-lane
        // on the idle DS pipe; wave-boundary lane reloads them (1/64 lanes,
        // L1-hit). p==0 clamps to 0 -- those values are never selected
        // (columns 1-3's parents are all column 0 -> window index >= 4).
        float tpy = __shfl_up(v.tb.y, 1);
        float tpz = __shfl_up(v.tb.z, 1);
        float tpw = __shfl_up(v.tb.w, 1);
        if (ln == 0u) {
            const unsigned e = 8u * p;
            const unsigned b = (e >= 3u) ? e - 3u : 0u;
            tpy = targets[b];
            tpz = targets[b + 1u];
            tpw = targets[b + 2u];
        }

        // Window of targets, flat elements 8p-3 .. 8p+7:
        //  w[1]=tpy w[2]=tpz w[3]=tpw | w[4..7]=ta | w[8..11]=tb
        const float xs[8] = {v.xa.x, v.xa.y, v.xa.z, v.xa.w,
                             v.xb.x, v.xb.y, v.xb.z, v.xb.w};
        const float ts[8] = {v.ta.x, v.ta.y, v.ta.z, v.ta.w,
                             v.tb.x, v.tb.y, v.tb.z, v.tb.w};
        const float tpar[8] = {
            parsel(d[0], tpw,    tpz,    tpy),
            parsel(d[1], v.ta.x, tpw,    tpz),
            parsel(d[2], v.ta.y, v.ta.x, tpw),
            parsel(d[3], v.ta.z, v.ta.y, v.ta.x),
            parsel(d[4], v.ta.w, v.ta.z, v.ta.y),
            parsel(d[5], v.tb.x, v.ta.w, v.ta.z),
            parsel(d[6], v.tb.y, v.tb.x, v.ta.w),
            parsel(d[7], v.tb.z, v.tb.y, v.tb.x)};
        float a = 0.0f;
        #pragma unroll
        for (int j = 0; j < 8; ++j) {
            const float x = xs[j], t = ts[j];
            // Binary targets (t in {0,1}): e = exp(-x*(2t-1));
            // bce = ln(1+e); pt = 1/(1+e); 1-pt = e*pt.   (R5-verified math)
            const float sgn = __builtin_fmaf(2.0f, t, -1.0f);
            const float e   = __expf(-x * sgn);
            const float den = 1.0f + e;
            const float pt  = __builtin_amdgcn_rcpf(den);
            const float bce = __logf(den);
            const float omp = e * pt;                  // 1 - pt
            const float fo  = omp * omp * bce;         // focal / ALPHA
            float w = __builtin_fmaf(t, 0.375f, 0.1875f); // ALPHA * class weight
            const bool dbl = (d[j] != 0u) & (x > 0.5f) & (tpar[j] < 0.5f);
            w = dbl ? w + w : w;                       // (1 + penalty) factor
            a = __builtin_fmaf(fo, w, a);
        }
        acc += valid ? a : 0.0f;
    };

    // R12/R5's two-stage structure (best measured config).
    unsigned p = g0;
    P4 cur, nxt;
    LOAD(p, cur);                                     // g0 < n8 always
    for (unsigned it = 1u; it < niter; ++it) {
        const unsigned pn = p + stride;
        LOAD((pn < n8) ? pn : (n8 - 1u), nxt);        // clamped (masked later)
        COMP(cur, p, true);                           // p < n8 guaranteed here
        cur = nxt;
        p = pn;
    }
    COMP(cur, (p < n8) ? p : (n8 - 1u), p < n8);      // tail mask

    // 64-lane shuffle reduce -> 4-word LDS -> one PLAIN STORE per block
    // (same-address atomics were R1-R11's serial tail).
    #pragma unroll
    for (int off = 32; off > 0; off >>= 1)
        acc += __shfl_down(acc, off);

    const int wid = tid >> 6;
    if (ln == 0u) wsum[wid] = acc;
    __syncthreads();
    if (tid == 0u)
        partials[blockIdx.x] = wsum[0] + wsum[1] + wsum[2] + wsum[3];
}

__global__ __launch_bounds__(256)
void reduce_kernel(const float* __restrict__ partials,
                   float* __restrict__ out,
                   unsigned nparts, float scale)
{
    __shared__ float wsum[4];
    const unsigned tid = threadIdx.x;
    float a = 0.0f;
    for (unsigned i = tid; i < nparts; i += 256u) a += partials[i];
    #pragma unroll
    for (int off = 32; off > 0; off >>= 1)
        a += __shfl_down(a, off);
    const int wid = tid >> 6;
    if ((tid & 63u) == 0u) wsum[wid] = a;
    __syncthreads();
    if (tid == 0u)
        out[0] = (wsum[0] + wsum[1] + wsum[2] + wsum[3]) * scale;
}

extern "C" void kernel_launch(void* const* d_in, const int* in_sizes, int n_in,
                              void* d_out, int out_size, void* d_ws, size_t ws_size,
                              hipStream_t stream)
{
    const float* logits  = (const float*)d_in[0];
    const float* targets = (const float*)d_in[1];
    float* out = (float*)d_out;
    float* ws  = (float*)d_ws;                   // 2050 floats of scratch

    const unsigned n  = (unsigned)in_sizes[0];   // 25,000,000 (divisible by 8)
    const unsigned n8 = n / 8u;                  // 3,125,000 float4-pairs
    const float scale = 1.0f / (float)n;

    // 2050 = 25*82: element stride (gridDim*256*8) ≡ 0 mod 25 -> per-thread
    // column phase loop-invariant; 6 batches per thread, tail masked.
    const unsigned nblocks = 2050u;
    const unsigned stride  = nblocks * 256u;
    const unsigned niter   = (n8 + stride - 1u) / stride;   // = 6

    // Stage 1 writes every ws[0..2049] each call; stage 2 reads them and
    // overwrites out[0] (covers the 0xAA poison) -- deterministic.
    hbfl_kernel<<<nblocks, 256, 0, stream>>>(logits, targets, ws, n8, niter);
    reduce_kernel<<<1, 256, 0, stream>>>(ws, out, nblocks, scale);
}

// Round 15
// 40.964 us; speedup vs baseline: 1.0506x; 1.0506x over previous
//
#include <hip/hip_runtime.h>

// 2-bit child->parent distance per column c (50-bit word): d = (DPACK >> 2c) & 3.
// d==0 -> not a child. Parent of column c is column c-d (d<=3, same row).
#define DPACK 0x00012493939124E4ULL

struct P5 { float4 xa, xb, ta, tb, tp; };

__device__ __forceinline__ float parsel(unsigned d, float w1, float w2, float w3) {
    return (d == 1u) ? w1 : (d == 2u) ? w2 : w3;   // caller masks d==0
}

__global__ __launch_bounds__(256)
void hbfl_kernel(const float* __restrict__ logits,
                 const float* __restrict__ targets,
                 float* __restrict__ partials,
                 unsigned n8, unsigned niter)
{
    __shared__ float wsum[4];

    const unsigned tid = threadIdx.x;
    const unsigned g0 = blockIdx.x * 256u + tid;      // pair-of-float4 index
    const unsigned stride = gridDim.x * 256u;         // 2050*256: 8*stride % 25 == 0

    // Loop-invariant per-thread column phase (8 consecutive elements).
    const unsigned c0 = (8u * g0) % 25u;
    unsigned d[8];
    #pragma unroll
    for (int j = 0; j < 8; ++j) {
        unsigned c = c0 + (unsigned)j;
        c = (c >= 25u) ? c - 25u : c;
        d[j] = (unsigned)(DPACK >> (2u * c)) & 3u;    // constant-index access only
    }

    const float4* l4p = reinterpret_cast<const float4*>(logits);
    const float4* t4p = reinterpret_cast<const float4*>(targets);

    auto LOAD = [&](unsigned p, P5& v) {
        const unsigned q = 2u * p;
        v.xa = l4p[q];
        v.xb = l4p[q + 1u];
        v.ta = t4p[q];
        v.tb = t4p[q + 1u];
        v.tp = t4p[q - (unsigned)(q != 0u)];          // prev 16B (L1/L2-hit; clamped @0)
    };

    float acc = 0.0f;

    auto COMP = [&](const P5& v, bool valid) {
        // Window of targets, flat elements 8p-4 .. 8p+7:
        //  W: tp.x tp.y tp.z tp.w | ta.x ta.y ta.z ta.w | tb.x tb.y tb.z tb.w
        const float xs[8] = {v.xa.x, v.xa.y, v.xa.z, v.xa.w,
                             v.xb.x, v.xb.y, v.xb.z, v.xb.w};
        const float ts[8] = {v.ta.x, v.ta.y, v.ta.z, v.ta.w,
                             v.tb.x, v.tb.y, v.tb.z, v.tb.w};
        const float tpar[8] = {
            parsel(d[0], v.tp.w, v.tp.z, v.tp.y),
            parsel(d[1], v.ta.x, v.tp.w, v.tp.z),
            parsel(d[2], v.ta.y, v.ta.x, v.tp.w),
            parsel(d[3], v.ta.z, v.ta.y, v.ta.x),
            parsel(d[4], v.ta.w, v.ta.z, v.ta.y),
            parsel(d[5], v.tb.x, v.ta.w, v.ta.z),
            parsel(d[6], v.tb.y, v.tb.x, v.ta.w),
            parsel(d[7], v.tb.z, v.tb.y, v.tb.x)};
        float a = 0.0f;
        #pragma unroll
        for (int j = 0; j < 8; ++j) {
            const float x = xs[j], t = ts[j];
            // Binary targets (t in {0,1}): e = exp(-x*(2t-1));
            // bce = ln(1+e); pt = 1/(1+e); 1-pt = e*pt.   (R5-verified math)
            const float sgn = __builtin_fmaf(2.0f, t, -1.0f);
            const float e   = __expf(-x * sgn);
            const float den = 1.0f + e;
            const float pt  = __builtin_amdgcn_rcpf(den);
            const float bce = __logf(den);
            const float omp = e * pt;                  // 1 - pt
            const float fo  = omp * omp * bce;         // focal / ALPHA
            float w = __builtin_fmaf(t, 0.375f, 0.1875f); // ALPHA * class weight
            const bool dbl = (d[j] != 0u) & (x > 0.5f) & (tpar[j] < 0.5f);
            w = dbl ? w + w : w;                       // (1 + penalty) factor
            a = __builtin_fmaf(fo, w, a);
        }
        acc += valid ? a : 0.0f;
    };

    // Two-stage pipeline (R5/R12's best measured structure).
    unsigned p = g0;
    P5 cur, nxt;
    LOAD(p, cur);                                     // g0 < n8 always
    for (unsigned it = 1u; it < niter; ++it) {
        const unsigned pn = p + stride;
        LOAD((pn < n8) ? pn : (n8 - 1u), nxt);        // clamped (masked later)
        COMP(cur, true);                              // p < n8 guaranteed here
        cur = nxt;
        p = pn;
    }
    COMP(cur, p < n8);                                // tail mask

    // 64-lane shuffle reduce -> 4-word LDS -> one PLAIN STORE per block
    // (same-address atomicAdd across all blocks was the serial tail that
    //  dominated R1-R11: ~6-12 ns x nblocks, data-path independent).
    #pragma unroll
    for (int off = 32; off > 0; off >>= 1)
        acc += __shfl_down(acc, off);

    const int wid = tid >> 6;
    if ((tid & 63u) == 0u) wsum[wid] = acc;
    __syncthreads();
    if (tid == 0u)
        partials[blockIdx.x] = wsum[0] + wsum[1] + wsum[2] + wsum[3];
}

__global__ __launch_bounds__(256)
void reduce_kernel(const float* __restrict__ partials,
                   float* __restrict__ out,
                   unsigned nparts, float scale)
{
    __shared__ float wsum[4];
    const unsigned tid = threadIdx.x;
    float a = 0.0f;
    for (unsigned i = tid; i < nparts; i += 256u) a += partials[i];
    #pragma unroll
    for (int off = 32; off > 0; off >>= 1)
        a += __shfl_down(a, off);
    const int wid = tid >> 6;
    if ((tid & 63u) == 0u) wsum[wid] = a;
    __syncthreads();
    if (tid == 0u)
        out[0] = (wsum[0] + wsum[1] + wsum[2] + wsum[3]) * scale;
}

extern "C" void kernel_launch(void* const* d_in, const int* in_sizes, int n_in,
                              void* d_out, int out_size, void* d_ws, size_t ws_size,
                              hipStream_t stream)
{
    const float* logits  = (const float*)d_in[0];
    const float* targets = (const float*)d_in[1];
    float* out = (float*)d_out;
    float* ws  = (float*)d_ws;                   // 2050 floats of scratch

    const unsigned n  = (unsigned)in_sizes[0];   // 25,000,000 (divisible by 8)
    const unsigned n8 = n / 8u;                  // 3,125,000 float4-pairs
    const float scale = 1.0f / (float)n;

    // 2050 = 25*82: element stride (gridDim*256*8) ≡ 0 mod 25 -> per-thread
    // column phase loop-invariant; 6 batches per thread, tail masked.
    const unsigned nblocks = 2050u;
    const unsigned stride  = nblocks * 256u;
    const unsigned niter   = (n8 + stride - 1u) / stride;   // = 6

    // Stage 1 writes every ws[0..2049] each call; stage 2 reads them and
    // overwrites out[0] (covers the 0xAA poison) -- deterministic.
    hbfl_kernel<<<nblocks, 256, 0, stream>>>(logits, targets, ws, n8, niter);
    reduce_kernel<<<1, 256, 0, stream>>>(ws, out, nblocks, scale);
}

// Round 16
// 40.254 us; speedup vs baseline: 1.0692x; 1.0177x over previous
//
#include <hip/hip_runtime.h>

// 2-bit child->parent distance per column c (50-bit word): d = (DPACK >> 2c) & 3.
// d==0 -> not a child. Parent of column c is column c-d (d<=3, same row).
#define DPACK 0x00012493939124E4ULL

struct P5 { float4 xa, xb, ta, tb, tp; };

__device__ __forceinline__ float parsel(unsigned d, float w1, float w2, float w3) {
    return (d == 1u) ? w1 : (d == 2u) ? w2 : w3;   // caller masks d==0
}

// Rotate the 50-bit DPACK so bit pair j = d(column of element 8p+j).
__device__ __forceinline__ unsigned ddof(unsigned p) {
    const unsigned sh = 2u * ((8u * p) % 25u);           // 0..48, even
    return (unsigned)((DPACK >> sh) | (DPACK << (50u - sh)));
}

__global__ __launch_bounds__(256)
void hbfl_kernel(const float* __restrict__ logits,
                 const float* __restrict__ targets,
                 float* __restrict__ partials,
                 unsigned n8, unsigned niter)
{
    __shared__ float wsum[4];

    const unsigned tid = threadIdx.x;
    const unsigned g0 = blockIdx.x * 256u + tid;      // pair-of-float4 index
    const unsigned stride = gridDim.x * 256u;         // 2048*256 = 524288

    const float4* l4p = reinterpret_cast<const float4*>(logits);
    const float4* t4p = reinterpret_cast<const float4*>(targets);

    auto LOAD = [&](unsigned p, P5& v) {
        const unsigned q = 2u * p;
        v.xa = l4p[q];
        v.xb = l4p[q + 1u];
        v.ta = t4p[q];
        v.tb = t4p[q + 1u];
        v.tp = t4p[q - (unsigned)(q != 0u)];          // prev 16B (L1/L2-hit; clamped @0)
    };

    float acc = 0.0f;

    auto COMP = [&](const P5& v, unsigned dd, bool valid) {
        // Window of targets, flat elements 8p-4 .. 8p+7:
        //  W: tp.x tp.y tp.z tp.w | ta.x ta.y ta.z ta.w | tb.x tb.y tb.z tb.w
        const float xs[8] = {v.xa.x, v.xa.y, v.xa.z, v.xa.w,
                             v.xb.x, v.xb.y, v.xb.z, v.xb.w};
        const float ts[8] = {v.ta.x, v.ta.y, v.ta.z, v.ta.w,
                             v.tb.x, v.tb.y, v.tb.z, v.tb.w};
        const float tpar[8] = {
            parsel((dd >> 0) & 3u,  v.tp.w, v.tp.z, v.tp.y),
            parsel((dd >> 2) & 3u,  v.ta.x, v.tp.w, v.tp.z),
            parsel((dd >> 4) & 3u,  v.ta.y, v.ta.x, v.tp.w),
            parsel((dd >> 6) & 3u,  v.ta.z, v.ta.y, v.ta.x),
            parsel((dd >> 8) & 3u,  v.ta.w, v.ta.z, v.ta.y),
            parsel((dd >> 10) & 3u, v.tb.x, v.ta.w, v.ta.z),
            parsel((dd >> 12) & 3u, v.tb.y, v.tb.x, v.ta.w),
            parsel((dd >> 14) & 3u, v.tb.z, v.tb.y, v.tb.x)};
        float a = 0.0f;
        #pragma unroll
        for (int j = 0; j < 8; ++j) {
            const float x = xs[j], t = ts[j];
            // Binary targets (t in {0,1}): e = exp(-x*(2t-1));
            // bce = ln(1+e); pt = 1/(1+e); 1-pt = e*pt.   (R5-verified math)
            const float sgn = __builtin_fmaf(2.0f, t, -1.0f);
            const float e   = __expf(-x * sgn);
            const float den = 1.0f + e;
            const float pt  = __builtin_amdgcn_rcpf(den);
            const float bce = __logf(den);
            const float omp = e * pt;                  // 1 - pt
            const float fo  = omp * omp * bce;         // focal / ALPHA
            float w = __builtin_fmaf(t, 0.375f, 0.1875f); // ALPHA * class weight
            const unsigned dj = (dd >> (2 * j)) & 3u;
            const bool dbl = (dj != 0u) & (x > 0.5f) & (tpar[j] < 0.5f);
            w = dbl ? w + w : w;                       // (1 + penalty) factor
            a = __builtin_fmaf(fo, w, a);
        }
        acc += valid ? a : 0.0f;
    };

    // R12's two-stage structure; per-batch rotated DPACK (no mod-25 grid
    // constraint) so the grid can be exactly one co-residency wave.
    unsigned p = g0;
    unsigned ddc = ddof(p);
    P5 cur, nxt;
    LOAD(p, cur);                                     // g0 < n8 always
    for (unsigned it = 1u; it < niter; ++it) {
        const unsigned pn = p + stride;
        const unsigned pc = (pn < n8) ? pn : (n8 - 1u);
        LOAD(pc, nxt);                                // clamped (masked later)
        const unsigned ddn = ddof(pc);
        COMP(cur, ddc, true);                         // p < n8 guaranteed here
        cur = nxt;
        ddc = ddn;
        p = pn;
    }
    COMP(cur, ddc, p < n8);                           // tail mask

    // 64-lane shuffle reduce -> 4-word LDS -> one PLAIN STORE per block
    // (same-address atomicAdd across all blocks was the serial tail that
    //  dominated R1-R11: ~6-12 ns x nblocks, data-path independent).
    #pragma unroll
    for (int off = 32; off > 0; off >>= 1)
        acc += __shfl_down(acc, off);

    const int wid = tid >> 6;
    if ((tid & 63u) == 0u) wsum[wid] = acc;
    __syncthreads();
    if (tid == 0u)
        partials[blockIdx.x] = wsum[0] + wsum[1] + wsum[2] + wsum[3];
}

__global__ __launch_bounds__(256)
void reduce_kernel(const float* __restrict__ partials,
                   float* __restrict__ out,
                   unsigned nparts, float scale)
{
    __shared__ float wsum[4];
    const unsigned tid = threadIdx.x;
    float a = 0.0f;
    for (unsigned i = tid; i < nparts; i += 256u) a += partials[i];
    #pragma unroll
    for (int off = 32; off > 0; off >>= 1)
        a += __shfl_down(a, off);
    const int wid = tid >> 6;
    if ((tid & 63u) == 0u) wsum[wid] = a;
    __syncthreads();
    if (tid == 0u)
        out[0] = (wsum[0] + wsum[1] + wsum[2] + wsum[3]) * scale;
}

extern "C" void kernel_launch(void* const* d_in, const int* in_sizes, int n_in,
                              void* d_out, int out_size, void* d_ws, size_t ws_size,
                              hipStream_t stream)
{
    const float* logits  = (const float*)d_in[0];
    const float* targets = (const float*)d_in[1];
    float* out = (float*)d_out;
    float* ws  = (float*)d_ws;                   // 2048 floats of scratch

    const unsigned n  = (unsigned)in_sizes[0];   // 25,000,000 (divisible by 8)
    const unsigned n8 = n / 8u;                  // 3,125,000 float4-pairs
    const float scale = 1.0f / (float)n;

    // 2048 blocks = EXACTLY one co-residency wave (8 block-slots/CU x 256 CU)
    // -> zero straggler blocks (2050 left a 2-block serial tail on an idle
    // GPU). 6 batches per thread (6*524288 >= n8), tail masked.
    const unsigned nblocks = 2048u;
    const unsigned stride  = nblocks * 256u;
    const unsigned niter   = (n8 + stride - 1u) / stride;   // = 6

    // Stage 1 writes every ws[0..2047] each call; stage 2 reads them and
    // overwrites out[0] (covers the 0xAA poison) -- deterministic.
    hbfl_kernel<<<nblocks, 256, 0, stream>>>(logits, targets, ws, n8, niter);
    reduce_kernel<<<1, 256, 0, stream>>>(ws, out, nblocks, scale);
}